// Round 1
// baseline (219.714 us; speedup 1.0000x reference)
//
#include <hip/hip_runtime.h>
#include <hip/hip_bf16.h>
#include <math.h>

#define BATCH 4096
#define INDIM 512
#define NDIM  1024
#define NG    16

typedef __bf16 bf16_t;
typedef __bf16 bf16x8 __attribute__((ext_vector_type(8)));
typedef float  f32x4  __attribute__((ext_vector_type(4)));

__device__ __forceinline__ float gelu_exact(float v) {
    return 0.5f * v * (1.0f + erff(v * 0.70710678118654752440f));
}

// Deterministic per-genre bucketing: chunked histogram + prefix + ordered scatter.
// Single block, no atomics -> perm is bitwise deterministic.
__global__ __launch_bounds__(256)
void build_perm_kernel(const int* __restrict__ genre,
                       int* __restrict__ perm,
                       int* __restrict__ offsets /* NG+1 ints */) {
    __shared__ int cc[64][NG];
    __shared__ int gtot[NG];
    __shared__ int goff[NG];
    const int t = threadIdx.x;
    for (int i = t; i < 64 * NG; i += 256) (&cc[0][0])[i] = 0;
    __syncthreads();
    if (t < 64) {
        #pragma unroll 1
        for (int i = 0; i < 64; ++i) {
            int g = genre[t * 64 + i] & (NG - 1);
            cc[t][g] += 1;
        }
    }
    __syncthreads();
    if (t < NG) {
        int s = 0;
        #pragma unroll 1
        for (int c = 0; c < 64; ++c) { int v = cc[c][t]; cc[c][t] = s; s += v; }
        gtot[t] = s;
    }
    __syncthreads();
    if (t == 0) {
        int s = 0;
        for (int g = 0; g < NG; ++g) { goff[g] = s; offsets[g] = s; s += gtot[g]; }
        offsets[NG] = s;
    }
    __syncthreads();
    if (t < 64) {
        #pragma unroll 1
        for (int i = 0; i < 64; ++i) {
            int b = t * 64 + i;
            int g = genre[b] & (NG - 1);
            int pos = goff[g] + cc[t][g];
            cc[t][g] += 1;
            perm[pos] = b;
        }
    }
}

// 64x64 output tile, BK=64, 256 threads (4 waves, each 16 rows x 64 cols).
// A: fp32 [Mtot][K] (optionally gathered via perm). Bw: fp32 [K][N] (or [G][K][N]).
// C: fp32, optionally scattered via perm. bf16 MFMA, fp32 accumulate.
template<bool EXPERT, bool GATHER_A, bool GELU, bool SCATTER_OUT>
__global__ __launch_bounds__(256)
void gemm_kernel(const float* __restrict__ A,
                 const float* __restrict__ Bw,
                 const float* __restrict__ bias,
                 float* __restrict__ Cout,
                 int K,
                 const int* __restrict__ perm,
                 const int* __restrict__ offsets) {
    constexpr int N = NDIM;
    __shared__ bf16_t As[64][72];  // pad 72 -> 144B row stride (16B aligned, bank-spread)
    __shared__ bf16_t Bs[64][72];  // stored transposed: Bs[n][k]

    const int n0 = blockIdx.y * 64;
    int m0 = 0, mloc0 = 0, count = 0, gbase = 0;
    const float* Bptr = Bw;
    const float* biasptr = bias;

    if constexpr (EXPERT) {
        const int bx = blockIdx.x;
        int g = 0, accum = 0, cnt = 0;
        for (; g < NG; ++g) {
            cnt = offsets[g + 1] - offsets[g];
            int nt = (cnt + 63) >> 6;
            if (bx < accum + nt) break;
            accum += nt;
        }
        if (g >= NG) return;  // past the real tile total
        count = cnt;
        mloc0 = (bx - accum) * 64;
        gbase = offsets[g];
        m0 = gbase + mloc0;
        Bptr = Bw + (size_t)g * NDIM * NDIM;
        biasptr = bias + g * NDIM;
    } else {
        m0 = blockIdx.x * 64;
    }

    const int tid  = threadIdx.x;
    const int wave = tid >> 6;
    const int lane = tid & 63;
    const int l15  = lane & 15;
    const int kg   = lane >> 4;

    // A staging: thread -> (tile row sr, 16-wide k chunk skq)
    const int sr  = tid >> 2;
    const int skq = (tid & 3) << 4;
    int arow;
    if constexpr (EXPERT) {
        int rcl = mloc0 + sr;
        if (rcl >= count) rcl = count - 1;  // clamp tail rows inside this genre
        const int prow = gbase + rcl;
        arow = GATHER_A ? perm[prow] : prow;
    } else {
        arow = m0 + sr;
    }
    const float* Aptr = A + (size_t)arow * K + skq;

    // B staging: thread -> (k row bk, 16-wide n chunk nq), transposed into Bs
    const int bk = tid >> 2;
    const int nq = (tid & 3) << 4;
    const float* Bsrc = Bptr + (size_t)bk * N + (n0 + nq);

    f32x4 acc[4];
    #pragma unroll
    for (int n = 0; n < 4; ++n) acc[n] = (f32x4){0.f, 0.f, 0.f, 0.f};

    for (int k0 = 0; k0 < K; k0 += 64) {
        // ---- stage A: 16 fp32 -> 16 bf16, two 16B LDS writes
        {
            const float* p = Aptr + k0;
            float4 v0 = *(const float4*)(p + 0);
            float4 v1 = *(const float4*)(p + 4);
            float4 v2 = *(const float4*)(p + 8);
            float4 v3 = *(const float4*)(p + 12);
            bf16x8 w0, w1;
            w0[0] = (bf16_t)v0.x; w0[1] = (bf16_t)v0.y; w0[2] = (bf16_t)v0.z; w0[3] = (bf16_t)v0.w;
            w0[4] = (bf16_t)v1.x; w0[5] = (bf16_t)v1.y; w0[6] = (bf16_t)v1.z; w0[7] = (bf16_t)v1.w;
            w1[0] = (bf16_t)v2.x; w1[1] = (bf16_t)v2.y; w1[2] = (bf16_t)v2.z; w1[3] = (bf16_t)v2.w;
            w1[4] = (bf16_t)v3.x; w1[5] = (bf16_t)v3.y; w1[6] = (bf16_t)v3.z; w1[7] = (bf16_t)v3.w;
            *(bf16x8*)&As[sr][skq]     = w0;
            *(bf16x8*)&As[sr][skq + 8] = w1;
        }
        // ---- stage B (transpose into Bs[n][k]); scalar b16 writes (round-0 cost)
        {
            const float* p = Bsrc + (size_t)k0 * N;
            #pragma unroll
            for (int q = 0; q < 4; ++q) {
                float4 u = *(const float4*)(p + 4 * q);
                Bs[nq + 4 * q + 0][bk] = (bf16_t)u.x;
                Bs[nq + 4 * q + 1][bk] = (bf16_t)u.y;
                Bs[nq + 4 * q + 2][bk] = (bf16_t)u.z;
                Bs[nq + 4 * q + 3][bk] = (bf16_t)u.w;
            }
        }
        __syncthreads();
        #pragma unroll
        for (int kk = 0; kk < 64; kk += 32) {
            bf16x8 a = *(const bf16x8*)&As[wave * 16 + l15][kk + kg * 8];
            #pragma unroll
            for (int n = 0; n < 4; ++n) {
                bf16x8 b = *(const bf16x8*)&Bs[n * 16 + l15][kk + kg * 8];
                acc[n] = __builtin_amdgcn_mfma_f32_16x16x32_bf16(a, b, acc[n], 0, 0, 0);
            }
        }
        __syncthreads();
    }

    // ---- epilogue: bias (+ GELU), masked / scattered fp32 store
    const int trow = wave * 16 + kg * 4;
    #pragma unroll
    for (int n = 0; n < 4; ++n) {
        const int col = n0 + n * 16 + l15;
        const float bv = biasptr[col];
        #pragma unroll
        for (int r = 0; r < 4; ++r) {
            const int rl = trow + r;
            bool valid = true;
            if constexpr (EXPERT) valid = (mloc0 + rl) < count;
            if (!valid) continue;
            float v = acc[n][r] + bv;
            if constexpr (GELU) v = gelu_exact(v);
            int grow = m0 + rl;
            if constexpr (SCATTER_OUT) grow = perm[grow];
            Cout[(size_t)grow * N + col] = v;
        }
    }
}

extern "C" void kernel_launch(void* const* d_in, const int* in_sizes, int n_in,
                              void* d_out, int out_size, void* d_ws, size_t ws_size,
                              hipStream_t stream) {
    const float* x     = (const float*)d_in[0];
    const int*   genre = (const int*)  d_in[1];
    const float* W1    = (const float*)d_in[2];
    const float* b1    = (const float*)d_in[3];
    const float* W2    = (const float*)d_in[4];
    const float* b2    = (const float*)d_in[5];
    const float* Wa    = (const float*)d_in[6];
    const float* ba    = (const float*)d_in[7];
    const float* Wb    = (const float*)d_in[8];
    const float* bb    = (const float*)d_in[9];
    float* out = (float*)d_out;

    char* ws = (char*)d_ws;
    float* s1      = (float*)(ws);                               // 16 MB [4096][1024] fp32
    float* s       = (float*)(ws + (size_t)(16 << 20));          // 16 MB
    float* h       = (float*)(ws + (size_t)(32 << 20));          // 16 MB (genre-permuted rows)
    int*   perm    = (int*)  (ws + (size_t)(48 << 20));          // 16 KB
    int*   offsets = (int*)  (ws + (size_t)(48 << 20) + 65536);  // NG+1 ints

    build_perm_kernel<<<1, 256, 0, stream>>>(genre, perm, offsets);

    // trunk: s1 = gelu(x @ W1 + b1)
    gemm_kernel<false, false, true, false><<<dim3(64, 16), 256, 0, stream>>>(
        x, W1, b1, s1, INDIM, nullptr, nullptr);
    // trunk: s = gelu(s1 @ W2 + b2)
    gemm_kernel<false, false, true, false><<<dim3(64, 16), 256, 0, stream>>>(
        s1, W2, b2, s, NDIM, nullptr, nullptr);
    // experts: h[perm-space] = gelu(s[perm] @ Wa[g] + ba[g])   (gathered A, masked store)
    gemm_kernel<true, true, true, false><<<dim3(80, 16), 256, 0, stream>>>(
        s, Wa, ba, h, NDIM, perm, offsets);
    // experts: out[perm] = h @ Wb[g] + bb[g]                   (scattered store)
    gemm_kernel<true, false, false, true><<<dim3(80, 16), 256, 0, stream>>>(
        h, Wb, bb, out, NDIM, perm, offsets);
}

// Round 2
// 199.767 us; speedup vs baseline: 1.0998x; 1.0998x over previous
//
#include <hip/hip_runtime.h>
#include <hip/hip_bf16.h>
#include <math.h>

#define BATCH 4096
#define INDIM 512
#define NDIM  1024
#define NG    16

typedef __bf16 bf16_t;
typedef __bf16 bf16x8 __attribute__((ext_vector_type(8)));
typedef float  f32x4  __attribute__((ext_vector_type(4)));
typedef unsigned int u32;
typedef unsigned int u32x4 __attribute__((ext_vector_type(4)));

__device__ __forceinline__ float gelu_exact(float v) {
    return 0.5f * v * (1.0f + erff(v * 0.70710678118654752440f));
}

__device__ __forceinline__ void gload_lds16(const void* g, void* l) {
    __builtin_amdgcn_global_load_lds((const __attribute__((address_space(1))) void*)g,
                                     (__attribute__((address_space(3))) void*)l,
                                     16, 0, 0);
}

// ---------------- deterministic per-genre bucketing (unchanged) ----------------
__global__ __launch_bounds__(256)
void build_perm_kernel(const int* __restrict__ genre,
                       int* __restrict__ perm,
                       int* __restrict__ offsets /* NG+1 ints */) {
    __shared__ int cc[64][NG];
    __shared__ int gtot[NG];
    __shared__ int goff[NG];
    const int t = threadIdx.x;
    for (int i = t; i < 64 * NG; i += 256) (&cc[0][0])[i] = 0;
    __syncthreads();
    if (t < 64) {
        #pragma unroll 1
        for (int i = 0; i < 64; ++i) {
            int g = genre[t * 64 + i] & (NG - 1);
            cc[t][g] += 1;
        }
    }
    __syncthreads();
    if (t < NG) {
        int s = 0;
        #pragma unroll 1
        for (int c = 0; c < 64; ++c) { int v = cc[c][t]; cc[c][t] = s; s += v; }
        gtot[t] = s;
    }
    __syncthreads();
    if (t == 0) {
        int s = 0;
        for (int g = 0; g < NG; ++g) { goff[g] = s; offsets[g] = s; s += gtot[g]; }
        offsets[NG] = s;
    }
    __syncthreads();
    if (t < 64) {
        #pragma unroll 1
        for (int i = 0; i < 64; ++i) {
            int b = t * 64 + i;
            int g = genre[b] & (NG - 1);
            int pos = goff[g] + cc[t][g];
            cc[t][g] += 1;
            perm[pos] = b;
        }
    }
}

// ---------------- x: fp32 -> bf16 ----------------
__global__ __launch_bounds__(256)
void convert_x_kernel(const float* __restrict__ src, bf16_t* __restrict__ dst) {
    const int i = (blockIdx.x * 256 + threadIdx.x) * 8;  // grid sized exactly
    float4 a = *(const float4*)&src[i];
    float4 b = *(const float4*)&src[i + 4];
    bf16x8 w;
    w[0] = (bf16_t)a.x; w[1] = (bf16_t)a.y; w[2] = (bf16_t)a.z; w[3] = (bf16_t)a.w;
    w[4] = (bf16_t)b.x; w[5] = (bf16_t)b.y; w[6] = (bf16_t)b.z; w[7] = (bf16_t)b.w;
    *(bf16x8*)&dst[i] = w;
}

// ---------------- weight transpose+convert: fp32 [K][N] -> bf16 [N][K] ----------------
__device__ __forceinline__ u32 pkbf(float a, float b) {
    union { bf16_t h[2]; u32 v; } x;
    x.h[0] = (bf16_t)a; x.h[1] = (bf16_t)b;
    return x.v;
}

__global__ __launch_bounds__(256)
void transpose_w_kernel(const float* __restrict__ src, bf16_t* __restrict__ dst,
                        int K, int N) {
    __shared__ u32 T[64][17];  // [n][kpair], pad 17 -> 2-way-max bank aliasing
    const int k0 = blockIdx.x * 32;
    const int n0 = blockIdx.y * 64;
    const size_t slab = (size_t)blockIdx.z * (size_t)K * (size_t)N;
    src += slab;
    dst += slab;
    const int t = threadIdx.x;
    {
        const int kr = (t >> 4) * 2;       // 0..30
        const int nc = (t & 15) * 4;       // 0..60
        const float* p0 = src + (size_t)(k0 + kr) * N + n0 + nc;
        const float* p1 = p0 + N;
        float4 r0 = *(const float4*)p0;
        float4 r1 = *(const float4*)p1;
        const int kp = t >> 4;
        T[nc + 0][kp] = pkbf(r0.x, r1.x);
        T[nc + 1][kp] = pkbf(r0.y, r1.y);
        T[nc + 2][kp] = pkbf(r0.z, r1.z);
        T[nc + 3][kp] = pkbf(r0.w, r1.w);
    }
    __syncthreads();
    {
        const int n = t >> 2;          // 0..63
        const int c = t & 3;           // 16B chunk of the 64B row
        u32x4 v;
        v.x = T[n][c * 4 + 0];
        v.y = T[n][c * 4 + 1];
        v.z = T[n][c * 4 + 2];
        v.w = T[n][c * 4 + 3];
        *(u32x4*)((char*)dst + ((size_t)(n0 + n) * K + k0 + c * 8) * 2) = v;
    }
}

// ---------------- 128x128 MFMA GEMM (m97 structure) ----------------
// A: bf16 [M][K] (optionally row-gathered via perm). Bt: bf16 [N][K] (or [G][N][K]).
// 256 threads = 4 waves in 2x2, each wave 64x64 (4x4 fragments of 16x16x32).
template<bool EXPERT, bool GATHER_A, bool GELU_OUT, bool SCATTER_OUT, bool OUT_BF16>
__global__ __launch_bounds__(256)
void gemm128_kernel(const bf16_t* __restrict__ A,
                    const bf16_t* __restrict__ Bt,
                    const float* __restrict__ bias,
                    void* __restrict__ Cout,
                    int K,
                    const int* __restrict__ perm,
                    const int* __restrict__ offsets) {
    constexpr int N = NDIM;
    __shared__ bf16_t As[128 * 64];  // linear [row][k], row stride 128B
    __shared__ bf16_t Bs[128 * 64];  // linear [n][k]

    const int n0 = blockIdx.y * 128;
    int m0 = 0, mloc0 = 0, count = 1 << 30, gbase = 0;
    const bf16_t* Bp = Bt;
    const float* biasp = bias;

    if constexpr (EXPERT) {
        const int bx = blockIdx.x;
        int g = 0, accum = 0, cnt = 0;
        for (; g < NG; ++g) {
            cnt = offsets[g + 1] - offsets[g];
            int nt = (cnt + 127) >> 7;
            if (bx < accum + nt) break;
            accum += nt;
        }
        if (g >= NG) return;  // beyond real tile total
        count = cnt;
        mloc0 = (bx - accum) * 128;
        gbase = offsets[g];
        m0 = gbase + mloc0;
        Bp = Bt + (size_t)g * N * NDIM;
        biasp = bias + g * N;
    } else {
        m0 = blockIdx.x * 128;
    }

    const int tid  = threadIdx.x;
    const int wave = tid >> 6;
    const int lane = tid & 63;
    const int l15  = lane & 15;
    const int l16  = lane >> 4;
    const int wr   = wave >> 1;
    const int wc   = wave & 1;

    // staging source pointers (fixed across K-loop): issue i of wave w covers
    // rows (w*4+i)*8 .. +8; lane l -> row +(l>>3), 16B chunk (l&7).
    const char* aptr[4];
    const char* bptr[4];
    #pragma unroll
    for (int i = 0; i < 4; ++i) {
        const int row = wave * 32 + i * 8 + (lane >> 3);
        int arow;
        if constexpr (EXPERT) {
            int rcl = mloc0 + row;
            if (rcl >= count) rcl = count - 1;   // clamp tail inside genre
            arow = GATHER_A ? perm[gbase + rcl] : (gbase + rcl);
        } else {
            arow = m0 + row;
        }
        aptr[i] = (const char*)(A + (size_t)arow * K) + (lane & 7) * 16;
        bptr[i] = (const char*)(Bp + (size_t)(n0 + row) * K) + (lane & 7) * 16;
    }

    f32x4 acc[4][4];
    #pragma unroll
    for (int m = 0; m < 4; ++m)
        #pragma unroll
        for (int n = 0; n < 4; ++n)
            acc[m][n] = (f32x4){0.f, 0.f, 0.f, 0.f};

    for (int k0 = 0; k0 < K; k0 += 64) {
        // ---- async stage: 8 x global_load_lds(16B) per thread-slot
        #pragma unroll
        for (int i = 0; i < 4; ++i) {
            gload_lds16(aptr[i] + (size_t)k0 * 2, (char*)As + (wave * 4 + i) * 1024);
            gload_lds16(bptr[i] + (size_t)k0 * 2, (char*)Bs + (wave * 4 + i) * 1024);
        }
        __syncthreads();   // compiler drains vmcnt(0) before barrier

        #pragma unroll
        for (int kk = 0; kk < 2; ++kk) {
            bf16x8 a[4], b[4];
            #pragma unroll
            for (int m = 0; m < 4; ++m)
                a[m] = *(const bf16x8*)&As[(wr * 64 + m * 16 + l15) * 64 + kk * 32 + l16 * 8];
            #pragma unroll
            for (int n = 0; n < 4; ++n)
                b[n] = *(const bf16x8*)&Bs[(wc * 64 + n * 16 + l15) * 64 + kk * 32 + l16 * 8];
            #pragma unroll
            for (int m = 0; m < 4; ++m)
                #pragma unroll
                for (int n = 0; n < 4; ++n)
                    acc[m][n] = __builtin_amdgcn_mfma_f32_16x16x32_bf16(a[m], b[n], acc[m][n], 0, 0, 0);
        }
        __syncthreads();
    }

    // ---- epilogue: bias (+GELU), masked/scattered store
    #pragma unroll
    for (int n = 0; n < 4; ++n) {
        const int col = n0 + wc * 64 + n * 16 + l15;
        const float bv = biasp[col];
        #pragma unroll
        for (int m = 0; m < 4; ++m) {
            #pragma unroll
            for (int r = 0; r < 4; ++r) {
                const int row_local = wr * 64 + m * 16 + l16 * 4 + r;
                if constexpr (EXPERT) {
                    if (mloc0 + row_local >= count) continue;
                }
                float v = acc[m][n][r] + bv;
                if constexpr (GELU_OUT) v = gelu_exact(v);
                int orow = m0 + row_local;
                if constexpr (SCATTER_OUT) orow = perm[orow];
                if constexpr (OUT_BF16)
                    ((bf16_t*)Cout)[(size_t)orow * N + col] = (bf16_t)v;
                else
                    ((float*)Cout)[(size_t)orow * N + col] = v;
            }
        }
    }
}

extern "C" void kernel_launch(void* const* d_in, const int* in_sizes, int n_in,
                              void* d_out, int out_size, void* d_ws, size_t ws_size,
                              hipStream_t stream) {
    const float* x     = (const float*)d_in[0];
    const int*   genre = (const int*)  d_in[1];
    const float* W1    = (const float*)d_in[2];
    const float* b1    = (const float*)d_in[3];
    const float* W2    = (const float*)d_in[4];
    const float* b2    = (const float*)d_in[5];
    const float* Wa    = (const float*)d_in[6];
    const float* ba    = (const float*)d_in[7];
    const float* Wb    = (const float*)d_in[8];
    const float* bb    = (const float*)d_in[9];
    float* out = (float*)d_out;

    char* ws = (char*)d_ws;
    const size_t MB = 1 << 20;
    bf16_t* W1t = (bf16_t*)(ws);                 // 1 MB  [1024][512]
    bf16_t* W2t = (bf16_t*)(ws + 1 * MB);        // 2 MB  [1024][1024]
    bf16_t* Wat = (bf16_t*)(ws + 3 * MB);        // 32 MB [16][1024][1024]
    bf16_t* Wbt = (bf16_t*)(ws + 35 * MB);       // 32 MB
    bf16_t* xb  = (bf16_t*)(ws + 67 * MB);       // 4 MB  [4096][512]
    bf16_t* s1b = (bf16_t*)(ws + 71 * MB);       // 8 MB  [4096][1024] (reused as h)
    bf16_t* sb  = (bf16_t*)(ws + 79 * MB);       // 8 MB
    int*    perm    = (int*)(ws + 87 * MB);      // 16 KB
    int*    offsets = (int*)(ws + 87 * MB + 65536);
    bf16_t* hb = s1b;  // s1 dead after GEMM2

    build_perm_kernel<<<1, 256, 0, stream>>>(genre, perm, offsets);
    convert_x_kernel<<<BATCH * INDIM / (256 * 8), 256, 0, stream>>>(x, xb);
    transpose_w_kernel<<<dim3(INDIM / 32, NDIM / 64, 1),  256, 0, stream>>>(W1, W1t, INDIM, NDIM);
    transpose_w_kernel<<<dim3(NDIM / 32, NDIM / 64, 1),   256, 0, stream>>>(W2, W2t, NDIM, NDIM);
    transpose_w_kernel<<<dim3(NDIM / 32, NDIM / 64, NG),  256, 0, stream>>>(Wa, Wat, NDIM, NDIM);
    transpose_w_kernel<<<dim3(NDIM / 32, NDIM / 64, NG),  256, 0, stream>>>(Wb, Wbt, NDIM, NDIM);

    // trunk: s1 = gelu(x @ W1 + b1)
    gemm128_kernel<false, false, true, false, true><<<dim3(32, 8), 256, 0, stream>>>(
        xb, W1t, b1, s1b, INDIM, nullptr, nullptr);
    // trunk: s = gelu(s1 @ W2 + b2)
    gemm128_kernel<false, false, true, false, true><<<dim3(32, 8), 256, 0, stream>>>(
        s1b, W2t, b2, sb, NDIM, nullptr, nullptr);
    // experts: h[perm-space] = gelu(s[perm] @ Wa[g] + ba[g])
    gemm128_kernel<true, true, true, false, true><<<dim3(48, 8), 256, 0, stream>>>(
        sb, Wat, ba, hb, NDIM, perm, offsets);
    // experts: out[perm] = h @ Wb[g] + bb[g]
    gemm128_kernel<true, false, false, true, false><<<dim3(48, 8), 256, 0, stream>>>(
        hb, Wbt, bb, out, NDIM, perm, offsets);
}

// Round 3
// 193.198 us; speedup vs baseline: 1.1372x; 1.0340x over previous
//
#include <hip/hip_runtime.h>
#include <hip/hip_bf16.h>
#include <math.h>

#define BATCH 4096
#define INDIM 512
#define NDIM  1024
#define NG    16

typedef __bf16 bf16_t;
typedef __bf16 bf16x8 __attribute__((ext_vector_type(8)));
typedef float  f32x4  __attribute__((ext_vector_type(4)));
typedef unsigned int u32;
typedef unsigned int u32x4 __attribute__((ext_vector_type(4)));

__device__ __forceinline__ float gelu_exact(float v) {
    return 0.5f * v * (1.0f + erff(v * 0.70710678118654752440f));
}

__device__ __forceinline__ void gload_lds16(const void* g, void* l) {
    __builtin_amdgcn_global_load_lds((const __attribute__((address_space(1))) void*)g,
                                     (__attribute__((address_space(3))) void*)l,
                                     16, 0, 0);
}

// ---------------- deterministic per-genre bucketing ----------------
__global__ __launch_bounds__(256)
void build_perm_kernel(const int* __restrict__ genre,
                       int* __restrict__ perm,
                       int* __restrict__ offsets /* NG+1 ints */) {
    __shared__ int cc[64][NG];
    __shared__ int gtot[NG];
    __shared__ int goff[NG];
    const int t = threadIdx.x;
    for (int i = t; i < 64 * NG; i += 256) (&cc[0][0])[i] = 0;
    __syncthreads();
    if (t < 64) {
        #pragma unroll 1
        for (int i = 0; i < 64; ++i) {
            int g = genre[t * 64 + i] & (NG - 1);
            cc[t][g] += 1;
        }
    }
    __syncthreads();
    if (t < NG) {
        int s = 0;
        #pragma unroll 1
        for (int c = 0; c < 64; ++c) { int v = cc[c][t]; cc[c][t] = s; s += v; }
        gtot[t] = s;
    }
    __syncthreads();
    if (t == 0) {
        int s = 0;
        for (int g = 0; g < NG; ++g) { goff[g] = s; offsets[g] = s; s += gtot[g]; }
        offsets[NG] = s;
    }
    __syncthreads();
    if (t < 64) {
        #pragma unroll 1
        for (int i = 0; i < 64; ++i) {
            int b = t * 64 + i;
            int g = genre[b] & (NG - 1);
            int pos = goff[g] + cc[t][g];
            cc[t][g] += 1;
            perm[pos] = b;
        }
    }
}

// ---------------- x: fp32 -> bf16 ----------------
__global__ __launch_bounds__(256)
void convert_x_kernel(const float* __restrict__ src, bf16_t* __restrict__ dst) {
    const int i = (blockIdx.x * 256 + threadIdx.x) * 8;  // grid sized exactly
    float4 a = *(const float4*)&src[i];
    float4 b = *(const float4*)&src[i + 4];
    bf16x8 w;
    w[0] = (bf16_t)a.x; w[1] = (bf16_t)a.y; w[2] = (bf16_t)a.z; w[3] = (bf16_t)a.w;
    w[4] = (bf16_t)b.x; w[5] = (bf16_t)b.y; w[6] = (bf16_t)b.z; w[7] = (bf16_t)b.w;
    *(bf16x8*)&dst[i] = w;
}

// ---------------- weight transpose+convert: fp32 [K][N] -> bf16 [N][K] ----------------
__device__ __forceinline__ u32 pkbf(float a, float b) {
    union { bf16_t h[2]; u32 v; } x;
    x.h[0] = (bf16_t)a; x.h[1] = (bf16_t)b;
    return x.v;
}

__global__ __launch_bounds__(256)
void transpose_w_kernel(const float* __restrict__ src, bf16_t* __restrict__ dst,
                        int K, int N) {
    __shared__ u32 T[64][17];  // [n][kpair], pad 17 -> bank-spread
    const int k0 = blockIdx.x * 32;
    const int n0 = blockIdx.y * 64;
    const size_t slab = (size_t)blockIdx.z * (size_t)K * (size_t)N;
    src += slab;
    dst += slab;
    const int t = threadIdx.x;
    {
        const int kr = (t >> 4) * 2;       // 0..30
        const int nc = (t & 15) * 4;       // 0..60
        const float* p0 = src + (size_t)(k0 + kr) * N + n0 + nc;
        const float* p1 = p0 + N;
        float4 r0 = *(const float4*)p0;
        float4 r1 = *(const float4*)p1;
        const int kp = t >> 4;
        T[nc + 0][kp] = pkbf(r0.x, r1.x);
        T[nc + 1][kp] = pkbf(r0.y, r1.y);
        T[nc + 2][kp] = pkbf(r0.z, r1.z);
        T[nc + 3][kp] = pkbf(r0.w, r1.w);
    }
    __syncthreads();
    {
        const int n = t >> 2;          // 0..63
        const int c = t & 3;           // 16B chunk of the 64B row
        u32x4 v;
        v.x = T[n][c * 4 + 0];
        v.y = T[n][c * 4 + 1];
        v.z = T[n][c * 4 + 2];
        v.w = T[n][c * 4 + 3];
        *(u32x4*)((char*)dst + ((size_t)(n0 + n) * K + k0 + c * 8) * 2) = v;
    }
}

// ---------------- 128x128 MFMA GEMM, 2-phase double-buffered pipeline ----------------
// A: bf16 [M][K] (optionally row-gathered via perm). Bt: bf16 [N][K] (or [G][N][K]).
// 256 threads = 4 waves in 2x2, each wave 64x64 (4x4 fragments of 16x16x32).
// Counted-vmcnt discipline (T3/T4 minimum recipe): STAGE(t+1) issued before
// waiting vmcnt(8) on STAGE(t); raw s_barrier with memory clobber.
template<bool EXPERT, bool GATHER_A, bool GELU_OUT, bool SCATTER_OUT, bool OUT_BF16>
__global__ __launch_bounds__(256)
void gemm128_kernel(const bf16_t* __restrict__ A,
                    const bf16_t* __restrict__ Bt,
                    const float* __restrict__ bias,
                    void* __restrict__ Cout,
                    int K,
                    const int* __restrict__ perm,
                    const int* __restrict__ offsets) {
    constexpr int N = NDIM;
    __shared__ bf16_t As[2][128 * 64];  // [row][k], row stride 128B, linear (gload_lds dest)
    __shared__ bf16_t Bs[2][128 * 64];  // [n][k]

    const int n0 = blockIdx.y * 128;
    int m0 = 0, mloc0 = 0, count = 1 << 30, gbase = 0;
    const bf16_t* Bp = Bt;
    const float* biasp = bias;

    if constexpr (EXPERT) {
        const int bx = blockIdx.x;
        int g = 0, accum = 0, cnt = 0;
        for (; g < NG; ++g) {
            cnt = offsets[g + 1] - offsets[g];
            int nt = (cnt + 127) >> 7;
            if (bx < accum + nt) break;
            accum += nt;
        }
        if (g >= NG) return;  // beyond real tile total (whole block exits pre-barrier)
        count = cnt;
        mloc0 = (bx - accum) * 128;
        gbase = offsets[g];
        m0 = gbase + mloc0;
        Bp = Bt + (size_t)g * N * NDIM;
        biasp = bias + g * N;
    } else {
        m0 = blockIdx.x * 128;
    }

    const int tid  = threadIdx.x;
    const int wave = tid >> 6;
    const int lane = tid & 63;
    const int l15  = lane & 15;
    const int l16  = lane >> 4;
    const int wr   = wave >> 1;
    const int wc   = wave & 1;

    // staging source pointers (fixed across K-loop): issue i of wave w covers
    // rows (w*4+i)*8 .. +8; lane l -> row +(l>>3), 16B chunk (l&7).
    const char* aptr[4];
    const char* bptr[4];
    #pragma unroll
    for (int i = 0; i < 4; ++i) {
        const int row = wave * 32 + i * 8 + (lane >> 3);
        int arow;
        if constexpr (EXPERT) {
            int rcl = mloc0 + row;
            if (rcl >= count) rcl = count - 1;   // clamp tail inside genre
            arow = GATHER_A ? perm[gbase + rcl] : (gbase + rcl);
        } else {
            arow = m0 + row;
        }
        aptr[i] = (const char*)(A + (size_t)arow * K) + (lane & 7) * 16;
        bptr[i] = (const char*)(Bp + (size_t)(n0 + row) * K) + (lane & 7) * 16;
    }

    f32x4 acc[4][4];
    #pragma unroll
    for (int m = 0; m < 4; ++m)
        #pragma unroll
        for (int n = 0; n < 4; ++n)
            acc[m][n] = (f32x4){0.f, 0.f, 0.f, 0.f};

    const int nsteps = K >> 6;

    // 8 x global_load_lds(16B) per thread per stage (4 A + 4 B)
    auto stage = [&](int buf, int t) {
        const size_t ko = (size_t)t * 128;  // 64 bf16 = 128 bytes along K
        #pragma unroll
        for (int i = 0; i < 4; ++i) {
            gload_lds16(aptr[i] + ko, (char*)&As[buf][0] + (wave * 4 + i) * 1024);
            gload_lds16(bptr[i] + ko, (char*)&Bs[buf][0] + (wave * 4 + i) * 1024);
        }
    };

    stage(0, 0);
    int cur = 0;
    for (int t = 0; t < nsteps; ++t) {
        if (t + 1 < nsteps) {
            stage(cur ^ 1, t + 1);
            // wait only for STAGE(t)'s 8 loads; STAGE(t+1)'s 8 stay in flight
            asm volatile("s_waitcnt vmcnt(8)" ::: "memory");
        } else {
            asm volatile("s_waitcnt vmcnt(0)" ::: "memory");
        }
        asm volatile("s_barrier" ::: "memory");

        #pragma unroll
        for (int kk = 0; kk < 2; ++kk) {
            bf16x8 a[4], b[4];
            #pragma unroll
            for (int m = 0; m < 4; ++m)
                a[m] = *(const bf16x8*)&As[cur][(wr * 64 + m * 16 + l15) * 64 + kk * 32 + l16 * 8];
            #pragma unroll
            for (int n = 0; n < 4; ++n)
                b[n] = *(const bf16x8*)&Bs[cur][(wc * 64 + n * 16 + l15) * 64 + kk * 32 + l16 * 8];
            #pragma unroll
            for (int m = 0; m < 4; ++m)
                #pragma unroll
                for (int n = 0; n < 4; ++n)
                    acc[m][n] = __builtin_amdgcn_mfma_f32_16x16x32_bf16(a[m], b[n], acc[m][n], 0, 0, 0);
        }
        asm volatile("s_barrier" ::: "memory");  // reads done before buf[cur] is re-staged
        cur ^= 1;
    }

    // ---- epilogue: bias (+GELU), masked/scattered store
    #pragma unroll
    for (int n = 0; n < 4; ++n) {
        const int col = n0 + wc * 64 + n * 16 + l15;
        const float bv = biasp[col];
        #pragma unroll
        for (int m = 0; m < 4; ++m) {
            #pragma unroll
            for (int r = 0; r < 4; ++r) {
                const int row_local = wr * 64 + m * 16 + l16 * 4 + r;
                if constexpr (EXPERT) {
                    if (mloc0 + row_local >= count) continue;
                }
                float v = acc[m][n][r] + bv;
                if constexpr (GELU_OUT) v = gelu_exact(v);
                int orow = m0 + row_local;
                if constexpr (SCATTER_OUT) orow = perm[orow];
                if constexpr (OUT_BF16)
                    ((bf16_t*)Cout)[(size_t)orow * N + col] = (bf16_t)v;
                else
                    ((float*)Cout)[(size_t)orow * N + col] = v;
            }
        }
    }
}

extern "C" void kernel_launch(void* const* d_in, const int* in_sizes, int n_in,
                              void* d_out, int out_size, void* d_ws, size_t ws_size,
                              hipStream_t stream) {
    const float* x     = (const float*)d_in[0];
    const int*   genre = (const int*)  d_in[1];
    const float* W1    = (const float*)d_in[2];
    const float* b1    = (const float*)d_in[3];
    const float* W2    = (const float*)d_in[4];
    const float* b2    = (const float*)d_in[5];
    const float* Wa    = (const float*)d_in[6];
    const float* ba    = (const float*)d_in[7];
    const float* Wb    = (const float*)d_in[8];
    const float* bb    = (const float*)d_in[9];
    float* out = (float*)d_out;

    char* ws = (char*)d_ws;
    const size_t MB = 1 << 20;
    bf16_t* W1t = (bf16_t*)(ws);                 // 1 MB  [1024][512]
    bf16_t* W2t = (bf16_t*)(ws + 1 * MB);        // 2 MB  [1024][1024]
    bf16_t* Wat = (bf16_t*)(ws + 3 * MB);        // 32 MB [16][1024][1024]
    bf16_t* Wbt = (bf16_t*)(ws + 35 * MB);       // 32 MB
    bf16_t* xb  = (bf16_t*)(ws + 67 * MB);       // 4 MB  [4096][512]
    bf16_t* s1b = (bf16_t*)(ws + 71 * MB);       // 8 MB  [4096][1024] (reused as h)
    bf16_t* sb  = (bf16_t*)(ws + 79 * MB);       // 8 MB
    int*    perm    = (int*)(ws + 87 * MB);      // 16 KB
    int*    offsets = (int*)(ws + 87 * MB + 65536);
    bf16_t* hb = s1b;  // s1 dead after GEMM2

    build_perm_kernel<<<1, 256, 0, stream>>>(genre, perm, offsets);
    convert_x_kernel<<<BATCH * INDIM / (256 * 8), 256, 0, stream>>>(x, xb);
    transpose_w_kernel<<<dim3(INDIM / 32, NDIM / 64, 1),  256, 0, stream>>>(W1, W1t, INDIM, NDIM);
    transpose_w_kernel<<<dim3(NDIM / 32, NDIM / 64, 1),   256, 0, stream>>>(W2, W2t, NDIM, NDIM);
    transpose_w_kernel<<<dim3(NDIM / 32, NDIM / 64, NG),  256, 0, stream>>>(Wa, Wat, NDIM, NDIM);
    transpose_w_kernel<<<dim3(NDIM / 32, NDIM / 64, NG),  256, 0, stream>>>(Wb, Wbt, NDIM, NDIM);

    // trunk: s1 = gelu(x @ W1 + b1)
    gemm128_kernel<false, false, true, false, true><<<dim3(32, 8), 256, 0, stream>>>(
        xb, W1t, b1, s1b, INDIM, nullptr, nullptr);
    // trunk: s = gelu(s1 @ W2 + b2)
    gemm128_kernel<false, false, true, false, true><<<dim3(32, 8), 256, 0, stream>>>(
        s1b, W2t, b2, sb, NDIM, nullptr, nullptr);
    // experts: h[perm-space] = gelu(s[perm] @ Wa[g] + ba[g])
    gemm128_kernel<true, true, true, false, true><<<dim3(48, 8), 256, 0, stream>>>(
        sb, Wat, ba, hb, NDIM, perm, offsets);
    // experts: out[perm] = h @ Wb[g] + bb[g]
    gemm128_kernel<true, false, false, true, false><<<dim3(48, 8), 256, 0, stream>>>(
        hb, Wbt, bb, out, NDIM, perm, offsets);
}

// Round 4
// 184.541 us; speedup vs baseline: 1.1906x; 1.0469x over previous
//
#include <hip/hip_runtime.h>
#include <hip/hip_bf16.h>
#include <math.h>

#define BATCH 4096
#define INDIM 512
#define NDIM  1024
#define NG    16

typedef __bf16 bf16_t;
typedef __bf16 bf16x8 __attribute__((ext_vector_type(8)));
typedef float  f32x4  __attribute__((ext_vector_type(4)));
typedef unsigned int u32;
typedef unsigned int u32x4 __attribute__((ext_vector_type(4)));

__device__ __forceinline__ float gelu_exact(float v) {
    return 0.5f * v * (1.0f + erff(v * 0.70710678118654752440f));
}

__device__ __forceinline__ void gload_lds16(const void* g, void* l) {
    __builtin_amdgcn_global_load_lds((const __attribute__((address_space(1))) void*)g,
                                     (__attribute__((address_space(3))) void*)l,
                                     16, 0, 0);
}

// ---------------- deterministic per-genre bucketing ----------------
__global__ __launch_bounds__(256)
void build_perm_kernel(const int* __restrict__ genre,
                       int* __restrict__ perm,
                       int* __restrict__ offsets /* NG+1 ints */) {
    __shared__ int cc[64][NG];
    __shared__ int gtot[NG];
    __shared__ int goff[NG];
    const int t = threadIdx.x;
    for (int i = t; i < 64 * NG; i += 256) (&cc[0][0])[i] = 0;
    __syncthreads();
    if (t < 64) {
        #pragma unroll 1
        for (int i = 0; i < 64; ++i) {
            int g = genre[t * 64 + i] & (NG - 1);
            cc[t][g] += 1;
        }
    }
    __syncthreads();
    if (t < NG) {
        int s = 0;
        #pragma unroll 1
        for (int c = 0; c < 64; ++c) { int v = cc[c][t]; cc[c][t] = s; s += v; }
        gtot[t] = s;
    }
    __syncthreads();
    if (t == 0) {
        int s = 0;
        for (int g = 0; g < NG; ++g) { goff[g] = s; offsets[g] = s; s += gtot[g]; }
        offsets[NG] = s;
    }
    __syncthreads();
    if (t < 64) {
        #pragma unroll 1
        for (int i = 0; i < 64; ++i) {
            int b = t * 64 + i;
            int g = genre[b] & (NG - 1);
            int pos = goff[g] + cc[t][g];
            cc[t][g] += 1;
            perm[pos] = b;
        }
    }
}

// ---------------- x: fp32 -> bf16 ----------------
__global__ __launch_bounds__(256)
void convert_x_kernel(const float* __restrict__ src, bf16_t* __restrict__ dst) {
    const int i = (blockIdx.x * 256 + threadIdx.x) * 8;  // grid sized exactly
    float4 a = *(const float4*)&src[i];
    float4 b = *(const float4*)&src[i + 4];
    bf16x8 w;
    w[0] = (bf16_t)a.x; w[1] = (bf16_t)a.y; w[2] = (bf16_t)a.z; w[3] = (bf16_t)a.w;
    w[4] = (bf16_t)b.x; w[5] = (bf16_t)b.y; w[6] = (bf16_t)b.z; w[7] = (bf16_t)b.w;
    *(bf16x8*)&dst[i] = w;
}

// ---------------- weight transpose+convert: fp32 [K][N] -> bf16 [N][K] ----------------
__device__ __forceinline__ u32 pkbf(float a, float b) {
    union { bf16_t h[2]; u32 v; } x;
    x.h[0] = (bf16_t)a; x.h[1] = (bf16_t)b;
    return x.v;
}

__global__ __launch_bounds__(256)
void transpose_w_kernel(const float* __restrict__ src, bf16_t* __restrict__ dst,
                        int K, int N) {
    __shared__ u32 T[64][17];  // [n][kpair], pad 17 -> bank-spread
    const int k0 = blockIdx.x * 32;
    const int n0 = blockIdx.y * 64;
    const size_t slab = (size_t)blockIdx.z * (size_t)K * (size_t)N;
    src += slab;
    dst += slab;
    const int t = threadIdx.x;
    {
        const int kr = (t >> 4) * 2;       // 0..30
        const int nc = (t & 15) * 4;       // 0..60
        const float* p0 = src + (size_t)(k0 + kr) * N + n0 + nc;
        const float* p1 = p0 + N;
        float4 r0 = *(const float4*)p0;
        float4 r1 = *(const float4*)p1;
        const int kp = t >> 4;
        T[nc + 0][kp] = pkbf(r0.x, r1.x);
        T[nc + 1][kp] = pkbf(r0.y, r1.y);
        T[nc + 2][kp] = pkbf(r0.z, r1.z);
        T[nc + 3][kp] = pkbf(r0.w, r1.w);
    }
    __syncthreads();
    {
        const int n = t >> 2;          // 0..63
        const int c = t & 3;           // 16B chunk of the 64B row
        u32x4 v;
        v.x = T[n][c * 4 + 0];
        v.y = T[n][c * 4 + 1];
        v.z = T[n][c * 4 + 2];
        v.w = T[n][c * 4 + 3];
        *(u32x4*)((char*)dst + ((size_t)(n0 + n) * K + k0 + c * 8) * 2) = v;
    }
}

// ---------------- 128x128 MFMA GEMM, 2-phase pipeline + T2 XOR swizzle ----------------
// A: bf16 [M][K] (optionally row-gathered via perm). Bt: bf16 [N][K] (or [G][N][K]).
// 256 threads = 4 waves in 2x2, each wave 64x64 (4x4 fragments of 16x16x32).
// LDS tile [row][64] has 128B row stride -> 16-way bank conflict if read linearly.
// Swizzle (rule #21, both-sides): LDS dest linear (gload_lds), 16B-chunk index of
// the GLOBAL source is XOR'd with (row&7); ds_read applies the same XOR.
template<bool EXPERT, bool GATHER_A, bool GELU_OUT, bool SCATTER_OUT, bool OUT_BF16>
__global__ __launch_bounds__(256)
void gemm128_kernel(const bf16_t* __restrict__ A,
                    const bf16_t* __restrict__ Bt,
                    const float* __restrict__ bias,
                    void* __restrict__ Cout,
                    int K,
                    const int* __restrict__ perm,
                    const int* __restrict__ offsets) {
    constexpr int N = NDIM;
    __shared__ bf16_t As[2][128 * 64];  // [row][k], row stride 128B, linear dest
    __shared__ bf16_t Bs[2][128 * 64];  // [n][k]

    const int n0 = blockIdx.y * 128;
    int m0 = 0, mloc0 = 0, count = 1 << 30, gbase = 0;
    const bf16_t* Bp = Bt;
    const float* biasp = bias;

    if constexpr (EXPERT) {
        const int bx = blockIdx.x;
        int g = 0, accum = 0, cnt = 0;
        for (; g < NG; ++g) {
            cnt = offsets[g + 1] - offsets[g];
            int nt = (cnt + 127) >> 7;
            if (bx < accum + nt) break;
            accum += nt;
        }
        if (g >= NG) return;  // beyond real tile total (whole block exits pre-barrier)
        count = cnt;
        mloc0 = (bx - accum) * 128;
        gbase = offsets[g];
        m0 = gbase + mloc0;
        Bp = Bt + (size_t)g * N * NDIM;
        biasp = bias + g * N;
    } else {
        m0 = blockIdx.x * 128;
    }

    const int tid  = threadIdx.x;
    const int wave = tid >> 6;
    const int lane = tid & 63;
    const int l15  = lane & 15;
    const int l16  = lane >> 4;
    const int wr   = wave >> 1;
    const int wc   = wave & 1;

    // staging: issue i of wave w covers LDS rows (w*4+i)*8..+8; lane l -> row
    // +(l>>3), LDS 16B-chunk (l&7). Source chunk is the swizzled one:
    // (l&7) ^ (row&7) = (l&7) ^ ((l>>3)&7)  (row&7 == (l>>3)&7 since i*8 aligns).
    const int srcoff = (((lane & 7) ^ ((lane >> 3) & 7)) * 16);
    const char* aptr[4];
    const char* bptr[4];
    #pragma unroll
    for (int i = 0; i < 4; ++i) {
        const int row = wave * 32 + i * 8 + (lane >> 3);
        int arow;
        if constexpr (EXPERT) {
            int rcl = mloc0 + row;
            if (rcl >= count) rcl = count - 1;   // clamp tail inside genre
            arow = GATHER_A ? perm[gbase + rcl] : (gbase + rcl);
        } else {
            arow = m0 + row;
        }
        aptr[i] = (const char*)(A + (size_t)arow * K) + srcoff;
        bptr[i] = (const char*)(Bp + (size_t)(n0 + row) * K) + srcoff;
    }

    f32x4 acc[4][4];
    #pragma unroll
    for (int m = 0; m < 4; ++m)
        #pragma unroll
        for (int n = 0; n < 4; ++n)
            acc[m][n] = (f32x4){0.f, 0.f, 0.f, 0.f};

    const int nsteps = K >> 6;

    // 8 x global_load_lds(16B) per thread per stage (4 A + 4 B)
    auto stage = [&](int buf, int t) {
        const size_t ko = (size_t)t * 128;  // 64 bf16 = 128 bytes along K
        #pragma unroll
        for (int i = 0; i < 4; ++i) {
            gload_lds16(aptr[i] + ko, (char*)&As[buf][0] + (wave * 4 + i) * 1024);
            gload_lds16(bptr[i] + ko, (char*)&Bs[buf][0] + (wave * 4 + i) * 1024);
        }
    };

    stage(0, 0);
    int cur = 0;
    for (int t = 0; t < nsteps; ++t) {
        if (t + 1 < nsteps) {
            stage(cur ^ 1, t + 1);
            // wait only for STAGE(t)'s 8 loads; STAGE(t+1)'s 8 stay in flight
            asm volatile("s_waitcnt vmcnt(8)" ::: "memory");
        } else {
            asm volatile("s_waitcnt vmcnt(0)" ::: "memory");
        }
        asm volatile("s_barrier" ::: "memory");

        #pragma unroll
        for (int kk = 0; kk < 2; ++kk) {
            bf16x8 a[4], b[4];
            #pragma unroll
            for (int m = 0; m < 4; ++m) {
                const int row = wr * 64 + m * 16 + l15;
                const int chunk = (kk * 4 + l16) ^ (lane & 7);  // swizzled read
                a[m] = *(const bf16x8*)&As[cur][row * 64 + chunk * 8];
            }
            #pragma unroll
            for (int n = 0; n < 4; ++n) {
                const int row = wc * 64 + n * 16 + l15;
                const int chunk = (kk * 4 + l16) ^ (lane & 7);
                b[n] = *(const bf16x8*)&Bs[cur][row * 64 + chunk * 8];
            }
            #pragma unroll
            for (int m = 0; m < 4; ++m)
                #pragma unroll
                for (int n = 0; n < 4; ++n)
                    acc[m][n] = __builtin_amdgcn_mfma_f32_16x16x32_bf16(a[m], b[n], acc[m][n], 0, 0, 0);
        }
        asm volatile("s_barrier" ::: "memory");  // reads done before buf[cur] is re-staged
        cur ^= 1;
    }

    // ---- epilogue: bias (+GELU), masked/scattered store
    #pragma unroll
    for (int n = 0; n < 4; ++n) {
        const int col = n0 + wc * 64 + n * 16 + l15;
        const float bv = biasp[col];
        #pragma unroll
        for (int m = 0; m < 4; ++m) {
            #pragma unroll
            for (int r = 0; r < 4; ++r) {
                const int row_local = wr * 64 + m * 16 + l16 * 4 + r;
                if constexpr (EXPERT) {
                    if (mloc0 + row_local >= count) continue;
                }
                float v = acc[m][n][r] + bv;
                if constexpr (GELU_OUT) v = gelu_exact(v);
                int orow = m0 + row_local;
                if constexpr (SCATTER_OUT) orow = perm[orow];
                if constexpr (OUT_BF16)
                    ((bf16_t*)Cout)[(size_t)orow * N + col] = (bf16_t)v;
                else
                    ((float*)Cout)[(size_t)orow * N + col] = v;
            }
        }
    }
}

extern "C" void kernel_launch(void* const* d_in, const int* in_sizes, int n_in,
                              void* d_out, int out_size, void* d_ws, size_t ws_size,
                              hipStream_t stream) {
    const float* x     = (const float*)d_in[0];
    const int*   genre = (const int*)  d_in[1];
    const float* W1    = (const float*)d_in[2];
    const float* b1    = (const float*)d_in[3];
    const float* W2    = (const float*)d_in[4];
    const float* b2    = (const float*)d_in[5];
    const float* Wa    = (const float*)d_in[6];
    const float* ba    = (const float*)d_in[7];
    const float* Wb    = (const float*)d_in[8];
    const float* bb    = (const float*)d_in[9];
    float* out = (float*)d_out;

    char* ws = (char*)d_ws;
    const size_t MB = 1 << 20;
    bf16_t* W1t = (bf16_t*)(ws);                 // 1 MB  [1024][512]
    bf16_t* W2t = (bf16_t*)(ws + 1 * MB);        // 2 MB  [1024][1024]
    bf16_t* Wat = (bf16_t*)(ws + 3 * MB);        // 32 MB [16][1024][1024]
    bf16_t* Wbt = (bf16_t*)(ws + 35 * MB);       // 32 MB
    bf16_t* xb  = (bf16_t*)(ws + 67 * MB);       // 4 MB  [4096][512]
    bf16_t* s1b = (bf16_t*)(ws + 71 * MB);       // 8 MB  [4096][1024] (reused as h)
    bf16_t* sb  = (bf16_t*)(ws + 79 * MB);       // 8 MB
    int*    perm    = (int*)(ws + 87 * MB);      // 16 KB
    int*    offsets = (int*)(ws + 87 * MB + 65536);
    bf16_t* hb = s1b;  // s1 dead after GEMM2

    build_perm_kernel<<<1, 256, 0, stream>>>(genre, perm, offsets);
    convert_x_kernel<<<BATCH * INDIM / (256 * 8), 256, 0, stream>>>(x, xb);
    transpose_w_kernel<<<dim3(INDIM / 32, NDIM / 64, 1),  256, 0, stream>>>(W1, W1t, INDIM, NDIM);
    transpose_w_kernel<<<dim3(NDIM / 32, NDIM / 64, 1),   256, 0, stream>>>(W2, W2t, NDIM, NDIM);
    transpose_w_kernel<<<dim3(NDIM / 32, NDIM / 64, NG),  256, 0, stream>>>(Wa, Wat, NDIM, NDIM);
    transpose_w_kernel<<<dim3(NDIM / 32, NDIM / 64, NG),  256, 0, stream>>>(Wb, Wbt, NDIM, NDIM);

    // trunk: s1 = gelu(x @ W1 + b1)
    gemm128_kernel<false, false, true, false, true><<<dim3(32, 8), 256, 0, stream>>>(
        xb, W1t, b1, s1b, INDIM, nullptr, nullptr);
    // trunk: s = gelu(s1 @ W2 + b2)
    gemm128_kernel<false, false, true, false, true><<<dim3(32, 8), 256, 0, stream>>>(
        s1b, W2t, b2, sb, NDIM, nullptr, nullptr);
    // experts: h[perm-space] = gelu(s[perm] @ Wa[g] + ba[g])
    gemm128_kernel<true, true, true, false, true><<<dim3(48, 8), 256, 0, stream>>>(
        sb, Wat, ba, hb, NDIM, perm, offsets);
    // experts: out[perm] = h @ Wb[g] + bb[g]
    gemm128_kernel<true, false, false, true, false><<<dim3(48, 8), 256, 0, stream>>>(
        hb, Wbt, bb, out, NDIM, perm, offsets);
}

// Round 5
// 154.447 us; speedup vs baseline: 1.4226x; 1.1948x over previous
//
#include <hip/hip_runtime.h>
#include <hip/hip_bf16.h>
#include <math.h>

#define BATCH 4096
#define INDIM 512
#define NDIM  1024
#define NG    16

typedef __bf16 bf16_t;
typedef __bf16 bf16x8 __attribute__((ext_vector_type(8)));
typedef float  f32x4  __attribute__((ext_vector_type(4)));
typedef unsigned int u32;
typedef unsigned int u32x4 __attribute__((ext_vector_type(4)));

__device__ __forceinline__ float gelu_exact(float v) {
    return 0.5f * v * (1.0f + erff(v * 0.70710678118654752440f));
}

__device__ __forceinline__ void gload_lds16(const void* g, void* l) {
    __builtin_amdgcn_global_load_lds((const __attribute__((address_space(1))) void*)g,
                                     (__attribute__((address_space(3))) void*)l,
                                     16, 0, 0);
}

// ---------------- deterministic per-genre bucketing ----------------
__global__ __launch_bounds__(256)
void build_perm_kernel(const int* __restrict__ genre,
                       int* __restrict__ perm,
                       int* __restrict__ offsets /* NG+1 ints */) {
    __shared__ int cc[64][NG];
    __shared__ int gtot[NG];
    __shared__ int goff[NG];
    const int t = threadIdx.x;
    for (int i = t; i < 64 * NG; i += 256) (&cc[0][0])[i] = 0;
    __syncthreads();
    if (t < 64) {
        #pragma unroll 1
        for (int i = 0; i < 64; ++i) {
            int g = genre[t * 64 + i] & (NG - 1);
            cc[t][g] += 1;
        }
    }
    __syncthreads();
    if (t < NG) {
        int s = 0;
        #pragma unroll 1
        for (int c = 0; c < 64; ++c) { int v = cc[c][t]; cc[c][t] = s; s += v; }
        gtot[t] = s;
    }
    __syncthreads();
    if (t == 0) {
        int s = 0;
        for (int g = 0; g < NG; ++g) { goff[g] = s; offsets[g] = s; s += gtot[g]; }
        offsets[NG] = s;
    }
    __syncthreads();
    if (t < 64) {
        #pragma unroll 1
        for (int i = 0; i < 64; ++i) {
            int b = t * 64 + i;
            int g = genre[b] & (NG - 1);
            int pos = goff[g] + cc[t][g];
            cc[t][g] += 1;
            perm[pos] = b;
        }
    }
}

// ---------------- x: fp32 -> bf16 ----------------
__global__ __launch_bounds__(256)
void convert_x_kernel(const float* __restrict__ src, bf16_t* __restrict__ dst) {
    const int i = (blockIdx.x * 256 + threadIdx.x) * 8;  // grid sized exactly
    float4 a = *(const float4*)&src[i];
    float4 b = *(const float4*)&src[i + 4];
    bf16x8 w;
    w[0] = (bf16_t)a.x; w[1] = (bf16_t)a.y; w[2] = (bf16_t)a.z; w[3] = (bf16_t)a.w;
    w[4] = (bf16_t)b.x; w[5] = (bf16_t)b.y; w[6] = (bf16_t)b.z; w[7] = (bf16_t)b.w;
    *(bf16x8*)&dst[i] = w;
}

// ---------------- weight transpose+convert: fp32 [K][N] -> bf16 [N][K] ----------------
__device__ __forceinline__ u32 pkbf(float a, float b) {
    union { bf16_t h[2]; u32 v; } x;
    x.h[0] = (bf16_t)a; x.h[1] = (bf16_t)b;
    return x.v;
}

__global__ __launch_bounds__(256)
void transpose_w_kernel(const float* __restrict__ src, bf16_t* __restrict__ dst,
                        int K, int N) {
    __shared__ u32 T[64][17];  // [n][kpair], pad 17 -> bank-spread
    const int k0 = blockIdx.x * 32;
    const int n0 = blockIdx.y * 64;
    const size_t slab = (size_t)blockIdx.z * (size_t)K * (size_t)N;
    src += slab;
    dst += slab;
    const int t = threadIdx.x;
    {
        const int kr = (t >> 4) * 2;       // 0..30
        const int nc = (t & 15) * 4;       // 0..60
        const float* p0 = src + (size_t)(k0 + kr) * N + n0 + nc;
        const float* p1 = p0 + N;
        float4 r0 = *(const float4*)p0;
        float4 r1 = *(const float4*)p1;
        const int kp = t >> 4;
        T[nc + 0][kp] = pkbf(r0.x, r1.x);
        T[nc + 1][kp] = pkbf(r0.y, r1.y);
        T[nc + 2][kp] = pkbf(r0.z, r1.z);
        T[nc + 3][kp] = pkbf(r0.w, r1.w);
    }
    __syncthreads();
    {
        const int n = t >> 2;          // 0..63
        const int c = t & 3;           // 16B chunk of the 64B row
        u32x4 v;
        v.x = T[n][c * 4 + 0];
        v.y = T[n][c * 4 + 1];
        v.z = T[n][c * 4 + 2];
        v.w = T[n][c * 4 + 3];
        *(u32x4*)((char*)dst + ((size_t)(n0 + n) * K + k0 + c * 8) * 2) = v;
    }
}

// ------- 128x128 MFMA GEMM, 512 threads (8 waves), 2-phase + T2 XOR swizzle -------
// A: bf16 [M][K] (optionally row-gathered via perm). Bt: bf16 [N][K] (or [G][N][K]).
// 8 waves in 2x4; each wave computes 64 rows x 32 cols (4x2 frags of 16x16x32).
// 2 waves/SIMD per block (vs 1 at 256 threads) -> TLP hides ds_read/vmcnt/barrier.
// Swizzle (rule #21): LDS dest linear (gload_lds), global-source 16B chunk XOR'd
// with (row&7); ds_read applies the same XOR. Counted vmcnt(4), never 0 mid-loop.
template<bool EXPERT, bool GATHER_A, bool GELU_OUT, bool SCATTER_OUT, bool OUT_BF16>
__global__ __launch_bounds__(512, 2)
void gemm128_kernel(const bf16_t* __restrict__ A,
                    const bf16_t* __restrict__ Bt,
                    const float* __restrict__ bias,
                    void* __restrict__ Cout,
                    int K,
                    const int* __restrict__ perm,
                    const int* __restrict__ offsets) {
    constexpr int N = NDIM;
    __shared__ bf16_t As[2][128 * 64];  // [row][k], row stride 128B, linear dest
    __shared__ bf16_t Bs[2][128 * 64];  // [n][k]

    const int n0 = blockIdx.y * 128;
    int m0 = 0, mloc0 = 0, count = 1 << 30, gbase = 0;
    const bf16_t* Bp = Bt;
    const float* biasp = bias;

    if constexpr (EXPERT) {
        const int bx = blockIdx.x;
        int g = 0, accum = 0, cnt = 0;
        for (; g < NG; ++g) {
            cnt = offsets[g + 1] - offsets[g];
            int nt = (cnt + 127) >> 7;
            if (bx < accum + nt) break;
            accum += nt;
        }
        if (g >= NG) return;  // beyond real tile total (whole block exits pre-barrier)
        count = cnt;
        mloc0 = (bx - accum) * 128;
        gbase = offsets[g];
        m0 = gbase + mloc0;
        Bp = Bt + (size_t)g * N * NDIM;
        biasp = bias + g * N;
    } else {
        m0 = blockIdx.x * 128;
    }

    const int tid  = threadIdx.x;
    const int wave = tid >> 6;
    const int lane = tid & 63;
    const int l15  = lane & 15;
    const int l16  = lane >> 4;
    const int wr   = wave >> 2;   // 0..1 -> 64-row band
    const int wc   = wave & 3;    // 0..3 -> 32-col band

    // staging: slot i covers LDS rows i*64 + (tid>>3); lane l -> in-row 16B chunk
    // (l&7). Swizzled global source chunk = (l&7) ^ (row&7) = (l&7) ^ ((l>>3)&7).
    const int srcoff = (((lane & 7) ^ ((lane >> 3) & 7)) * 16);
    const char* aptr[2];
    const char* bptr[2];
    #pragma unroll
    for (int i = 0; i < 2; ++i) {
        const int row = i * 64 + (tid >> 3);
        int arow;
        if constexpr (EXPERT) {
            int rcl = mloc0 + row;
            if (rcl >= count) rcl = count - 1;   // clamp tail inside genre
            arow = GATHER_A ? perm[gbase + rcl] : (gbase + rcl);
        } else {
            arow = m0 + row;
        }
        aptr[i] = (const char*)(A + (size_t)arow * K) + srcoff;
        bptr[i] = (const char*)(Bp + (size_t)(n0 + row) * K) + srcoff;
    }

    f32x4 acc[4][2];
    #pragma unroll
    for (int m = 0; m < 4; ++m)
        #pragma unroll
        for (int n = 0; n < 2; ++n)
            acc[m][n] = (f32x4){0.f, 0.f, 0.f, 0.f};

    const int nsteps = K >> 6;
    const int w1024 = wave * 1024;

    // 4 x global_load_lds(16B) per thread per stage (2 A + 2 B)
    auto stage = [&](int buf, int t) {
        const size_t ko = (size_t)t * 128;  // 64 bf16 = 128 bytes along K
        #pragma unroll
        for (int i = 0; i < 2; ++i) {
            gload_lds16(aptr[i] + ko, (char*)&As[buf][0] + i * 8192 + w1024);
            gload_lds16(bptr[i] + ko, (char*)&Bs[buf][0] + i * 8192 + w1024);
        }
    };

    stage(0, 0);
    int cur = 0;
    for (int t = 0; t < nsteps; ++t) {
        if (t + 1 < nsteps) {
            stage(cur ^ 1, t + 1);
            // wait only for STAGE(t)'s 4 loads; STAGE(t+1)'s 4 stay in flight
            asm volatile("s_waitcnt vmcnt(4)" ::: "memory");
        } else {
            asm volatile("s_waitcnt vmcnt(0)" ::: "memory");
        }
        asm volatile("s_barrier" ::: "memory");

        #pragma unroll
        for (int kk = 0; kk < 2; ++kk) {
            bf16x8 a[4], b[2];
            #pragma unroll
            for (int m = 0; m < 4; ++m) {
                const int row = wr * 64 + m * 16 + l15;
                const int chunk = (kk * 4 + l16) ^ (lane & 7);  // swizzled read
                a[m] = *(const bf16x8*)&As[cur][row * 64 + chunk * 8];
            }
            #pragma unroll
            for (int n = 0; n < 2; ++n) {
                const int row = wc * 32 + n * 16 + l15;
                const int chunk = (kk * 4 + l16) ^ (lane & 7);
                b[n] = *(const bf16x8*)&Bs[cur][row * 64 + chunk * 8];
            }
            #pragma unroll
            for (int m = 0; m < 4; ++m)
                #pragma unroll
                for (int n = 0; n < 2; ++n)
                    acc[m][n] = __builtin_amdgcn_mfma_f32_16x16x32_bf16(a[m], b[n], acc[m][n], 0, 0, 0);
        }
        asm volatile("s_barrier" ::: "memory");  // reads done before buf[cur] is re-staged
        cur ^= 1;
    }

    // ---- epilogue: bias (+GELU), masked/scattered store
    #pragma unroll
    for (int n = 0; n < 2; ++n) {
        const int col = n0 + wc * 32 + n * 16 + l15;
        const float bv = biasp[col];
        #pragma unroll
        for (int m = 0; m < 4; ++m) {
            #pragma unroll
            for (int r = 0; r < 4; ++r) {
                const int row_local = wr * 64 + m * 16 + l16 * 4 + r;
                if constexpr (EXPERT) {
                    if (mloc0 + row_local >= count) continue;
                }
                float v = acc[m][n][r] + bv;
                if constexpr (GELU_OUT) v = gelu_exact(v);
                int orow = m0 + row_local;
                if constexpr (SCATTER_OUT) orow = perm[orow];
                if constexpr (OUT_BF16)
                    ((bf16_t*)Cout)[(size_t)orow * N + col] = (bf16_t)v;
                else
                    ((float*)Cout)[(size_t)orow * N + col] = v;
            }
        }
    }
}

extern "C" void kernel_launch(void* const* d_in, const int* in_sizes, int n_in,
                              void* d_out, int out_size, void* d_ws, size_t ws_size,
                              hipStream_t stream) {
    const float* x     = (const float*)d_in[0];
    const int*   genre = (const int*)  d_in[1];
    const float* W1    = (const float*)d_in[2];
    const float* b1    = (const float*)d_in[3];
    const float* W2    = (const float*)d_in[4];
    const float* b2    = (const float*)d_in[5];
    const float* Wa    = (const float*)d_in[6];
    const float* ba    = (const float*)d_in[7];
    const float* Wb    = (const float*)d_in[8];
    const float* bb    = (const float*)d_in[9];
    float* out = (float*)d_out;

    char* ws = (char*)d_ws;
    const size_t MB = 1 << 20;
    bf16_t* W1t = (bf16_t*)(ws);                 // 1 MB  [1024][512]
    bf16_t* W2t = (bf16_t*)(ws + 1 * MB);        // 2 MB  [1024][1024]
    bf16_t* Wat = (bf16_t*)(ws + 3 * MB);        // 32 MB [16][1024][1024]
    bf16_t* Wbt = (bf16_t*)(ws + 35 * MB);       // 32 MB
    bf16_t* xb  = (bf16_t*)(ws + 67 * MB);       // 4 MB  [4096][512]
    bf16_t* s1b = (bf16_t*)(ws + 71 * MB);       // 8 MB  [4096][1024] (reused as h)
    bf16_t* sb  = (bf16_t*)(ws + 79 * MB);       // 8 MB
    int*    perm    = (int*)(ws + 87 * MB);      // 16 KB
    int*    offsets = (int*)(ws + 87 * MB + 65536);
    bf16_t* hb = s1b;  // s1 dead after GEMM2

    build_perm_kernel<<<1, 256, 0, stream>>>(genre, perm, offsets);
    convert_x_kernel<<<BATCH * INDIM / (256 * 8), 256, 0, stream>>>(x, xb);
    transpose_w_kernel<<<dim3(INDIM / 32, NDIM / 64, 1),  256, 0, stream>>>(W1, W1t, INDIM, NDIM);
    transpose_w_kernel<<<dim3(NDIM / 32, NDIM / 64, 1),   256, 0, stream>>>(W2, W2t, NDIM, NDIM);
    transpose_w_kernel<<<dim3(NDIM / 32, NDIM / 64, NG),  256, 0, stream>>>(Wa, Wat, NDIM, NDIM);
    transpose_w_kernel<<<dim3(NDIM / 32, NDIM / 64, NG),  256, 0, stream>>>(Wb, Wbt, NDIM, NDIM);

    // trunk: s1 = gelu(x @ W1 + b1)
    gemm128_kernel<false, false, true, false, true><<<dim3(32, 8), 512, 0, stream>>>(
        xb, W1t, b1, s1b, INDIM, nullptr, nullptr);
    // trunk: s = gelu(s1 @ W2 + b2)
    gemm128_kernel<false, false, true, false, true><<<dim3(32, 8), 512, 0, stream>>>(
        s1b, W2t, b2, sb, NDIM, nullptr, nullptr);
    // experts: h[perm-space] = gelu(s[perm] @ Wa[g] + ba[g])
    gemm128_kernel<true, true, true, false, true><<<dim3(48, 8), 512, 0, stream>>>(
        sb, Wat, ba, hb, NDIM, perm, offsets);
    // experts: out[perm] = h @ Wb[g] + bb[g]
    gemm128_kernel<true, false, false, true, false><<<dim3(48, 8), 512, 0, stream>>>(
        hb, Wbt, bb, out, NDIM, perm, offsets);
}

// Round 6
// 149.204 us; speedup vs baseline: 1.4726x; 1.0351x over previous
//
#include <hip/hip_runtime.h>
#include <hip/hip_bf16.h>
#include <math.h>

#define BATCH 4096
#define INDIM 512
#define NDIM  1024
#define NG    16

typedef __bf16 bf16_t;
typedef __bf16 bf16x8 __attribute__((ext_vector_type(8)));
typedef float  f32x4  __attribute__((ext_vector_type(4)));
typedef unsigned int u32;
typedef unsigned int u32x4 __attribute__((ext_vector_type(4)));

__device__ __forceinline__ float gelu_exact(float v) {
    return 0.5f * v * (1.0f + erff(v * 0.70710678118654752440f));
}

__device__ __forceinline__ void gload_lds16(const void* g, void* l) {
    __builtin_amdgcn_global_load_lds((const __attribute__((address_space(1))) void*)g,
                                     (__attribute__((address_space(3))) void*)l,
                                     16, 0, 0);
}

// ---------------- deterministic per-genre bucketing ----------------
__global__ __launch_bounds__(256)
void build_perm_kernel(const int* __restrict__ genre,
                       int* __restrict__ perm,
                       int* __restrict__ offsets /* NG+1 ints */) {
    __shared__ int cc[64][NG];
    __shared__ int gtot[NG];
    __shared__ int goff[NG];
    const int t = threadIdx.x;
    for (int i = t; i < 64 * NG; i += 256) (&cc[0][0])[i] = 0;
    __syncthreads();
    if (t < 64) {
        #pragma unroll 1
        for (int i = 0; i < 64; ++i) {
            int g = genre[t * 64 + i] & (NG - 1);
            cc[t][g] += 1;
        }
    }
    __syncthreads();
    if (t < NG) {
        int s = 0;
        #pragma unroll 1
        for (int c = 0; c < 64; ++c) { int v = cc[c][t]; cc[c][t] = s; s += v; }
        gtot[t] = s;
    }
    __syncthreads();
    if (t == 0) {
        int s = 0;
        for (int g = 0; g < NG; ++g) { goff[g] = s; offsets[g] = s; s += gtot[g]; }
        offsets[NG] = s;
    }
    __syncthreads();
    if (t < 64) {
        #pragma unroll 1
        for (int i = 0; i < 64; ++i) {
            int b = t * 64 + i;
            int g = genre[b] & (NG - 1);
            int pos = goff[g] + cc[t][g];
            cc[t][g] += 1;
            perm[pos] = b;
        }
    }
}

// ---------------- x: fp32 -> bf16 ----------------
__global__ __launch_bounds__(256)
void convert_x_kernel(const float* __restrict__ src, bf16_t* __restrict__ dst) {
    const int i = (blockIdx.x * 256 + threadIdx.x) * 8;  // grid sized exactly
    float4 a = *(const float4*)&src[i];
    float4 b = *(const float4*)&src[i + 4];
    bf16x8 w;
    w[0] = (bf16_t)a.x; w[1] = (bf16_t)a.y; w[2] = (bf16_t)a.z; w[3] = (bf16_t)a.w;
    w[4] = (bf16_t)b.x; w[5] = (bf16_t)b.y; w[6] = (bf16_t)b.z; w[7] = (bf16_t)b.w;
    *(bf16x8*)&dst[i] = w;
}

// ---------------- weight transpose+convert: fp32 [K][N] -> bf16 [N][K] ----------------
__device__ __forceinline__ u32 pkbf(float a, float b) {
    union { bf16_t h[2]; u32 v; } x;
    x.h[0] = (bf16_t)a; x.h[1] = (bf16_t)b;
    return x.v;
}

__global__ __launch_bounds__(256)
void transpose_w_kernel(const float* __restrict__ src, bf16_t* __restrict__ dst,
                        int K, int N) {
    __shared__ u32 T[64][17];  // [n][kpair], pad 17 -> bank-spread
    const int k0 = blockIdx.x * 32;
    const int n0 = blockIdx.y * 64;
    const size_t slab = (size_t)blockIdx.z * (size_t)K * (size_t)N;
    src += slab;
    dst += slab;
    const int t = threadIdx.x;
    {
        const int kr = (t >> 4) * 2;       // 0..30
        const int nc = (t & 15) * 4;       // 0..60
        const float* p0 = src + (size_t)(k0 + kr) * N + n0 + nc;
        const float* p1 = p0 + N;
        float4 r0 = *(const float4*)p0;
        float4 r1 = *(const float4*)p1;
        const int kp = t >> 4;
        T[nc + 0][kp] = pkbf(r0.x, r1.x);
        T[nc + 1][kp] = pkbf(r0.y, r1.y);
        T[nc + 2][kp] = pkbf(r0.z, r1.z);
        T[nc + 3][kp] = pkbf(r0.w, r1.w);
    }
    __syncthreads();
    {
        const int n = t >> 2;          // 0..63
        const int c = t & 3;           // 16B chunk of the 64B row
        u32x4 v;
        v.x = T[n][c * 4 + 0];
        v.y = T[n][c * 4 + 1];
        v.z = T[n][c * 4 + 2];
        v.w = T[n][c * 4 + 3];
        *(u32x4*)((char*)dst + ((size_t)(n0 + n) * K + k0 + c * 8) * 2) = v;
    }
}

// ---- 128x128 MFMA GEMM, 1024 threads (16 waves, 4x4), 2-phase + T2 XOR swizzle ----
// A: bf16 [M][K] (optionally row-gathered via perm). Bt: bf16 [N][K] (or [G][N][K]).
// Each wave computes 32x32 (2x2 frags of 16x16x32). 4 waves/SIMD per block ->
// TLP hides ds_read latency + barrier drain. Sync structure unchanged from r5:
// counted vmcnt (2 in flight per stage), raw s_barrier, both-sides XOR swizzle.
template<bool EXPERT, bool GATHER_A, bool GELU_OUT, bool SCATTER_OUT, bool OUT_BF16>
__global__ __launch_bounds__(1024, 4)
void gemm128_kernel(const bf16_t* __restrict__ A,
                    const bf16_t* __restrict__ Bt,
                    const float* __restrict__ bias,
                    void* __restrict__ Cout,
                    int K,
                    const int* __restrict__ perm,
                    const int* __restrict__ offsets) {
    constexpr int N = NDIM;
    __shared__ bf16_t As[2][128 * 64];  // [row][k], row stride 128B, linear dest
    __shared__ bf16_t Bs[2][128 * 64];  // [n][k]

    const int n0 = blockIdx.y * 128;
    int m0 = 0, mloc0 = 0, count = 1 << 30, gbase = 0;
    const bf16_t* Bp = Bt;
    const float* biasp = bias;

    if constexpr (EXPERT) {
        const int bx = blockIdx.x;
        int g = 0, accum = 0, cnt = 0;
        for (; g < NG; ++g) {
            cnt = offsets[g + 1] - offsets[g];
            int nt = (cnt + 127) >> 7;
            if (bx < accum + nt) break;
            accum += nt;
        }
        if (g >= NG) return;  // beyond real tile total (whole block exits pre-barrier)
        count = cnt;
        mloc0 = (bx - accum) * 128;
        gbase = offsets[g];
        m0 = gbase + mloc0;
        Bp = Bt + (size_t)g * N * NDIM;
        biasp = bias + g * N;
    } else {
        m0 = blockIdx.x * 128;
    }

    const int tid  = threadIdx.x;
    const int wave = tid >> 6;
    const int lane = tid & 63;
    const int l15  = lane & 15;
    const int l16  = lane >> 4;
    const int wr   = wave >> 2;   // 0..3 -> 32-row band
    const int wc   = wave & 3;    // 0..3 -> 32-col band

    // staging: thread t covers LDS row (t>>3), in-row 16B chunk (t&7).
    // Swizzled global source chunk = (t&7) ^ (row&7) = (t&7) ^ ((t>>3)&7).
    const int srow   = tid >> 3;
    const int srcoff = (((tid & 7) ^ ((tid >> 3) & 7)) * 16);
    int arow;
    if constexpr (EXPERT) {
        int rcl = mloc0 + srow;
        if (rcl >= count) rcl = count - 1;   // clamp tail inside genre
        arow = GATHER_A ? perm[gbase + rcl] : (gbase + rcl);
    } else {
        arow = m0 + srow;
    }
    const char* aptr = (const char*)(A + (size_t)arow * K) + srcoff;
    const char* bptr = (const char*)(Bp + (size_t)(n0 + srow) * K) + srcoff;

    f32x4 acc[2][2];
    #pragma unroll
    for (int m = 0; m < 2; ++m)
        #pragma unroll
        for (int n = 0; n < 2; ++n)
            acc[m][n] = (f32x4){0.f, 0.f, 0.f, 0.f};

    const int nsteps = K >> 6;
    const int w1024 = wave * 1024;

    // 2 x global_load_lds(16B) per thread per stage (1 A + 1 B)
    auto stage = [&](int buf, int t) {
        const size_t ko = (size_t)t * 128;  // 64 bf16 = 128 bytes along K
        gload_lds16(aptr + ko, (char*)&As[buf][0] + w1024);
        gload_lds16(bptr + ko, (char*)&Bs[buf][0] + w1024);
    };

    stage(0, 0);
    int cur = 0;
    for (int t = 0; t < nsteps; ++t) {
        if (t + 1 < nsteps) {
            stage(cur ^ 1, t + 1);
            // wait only for STAGE(t)'s 2 loads; STAGE(t+1)'s 2 stay in flight
            asm volatile("s_waitcnt vmcnt(2)" ::: "memory");
        } else {
            asm volatile("s_waitcnt vmcnt(0)" ::: "memory");
        }
        asm volatile("s_barrier" ::: "memory");

        #pragma unroll
        for (int kk = 0; kk < 2; ++kk) {
            bf16x8 a[2], b[2];
            #pragma unroll
            for (int m = 0; m < 2; ++m) {
                const int row = wr * 32 + m * 16 + l15;
                const int chunk = (kk * 4 + l16) ^ (lane & 7);  // swizzled read
                a[m] = *(const bf16x8*)&As[cur][row * 64 + chunk * 8];
            }
            #pragma unroll
            for (int n = 0; n < 2; ++n) {
                const int row = wc * 32 + n * 16 + l15;
                const int chunk = (kk * 4 + l16) ^ (lane & 7);
                b[n] = *(const bf16x8*)&Bs[cur][row * 64 + chunk * 8];
            }
            #pragma unroll
            for (int m = 0; m < 2; ++m)
                #pragma unroll
                for (int n = 0; n < 2; ++n)
                    acc[m][n] = __builtin_amdgcn_mfma_f32_16x16x32_bf16(a[m], b[n], acc[m][n], 0, 0, 0);
        }
        asm volatile("s_barrier" ::: "memory");  // reads done before buf[cur] is re-staged
        cur ^= 1;
    }

    // ---- epilogue: bias (+GELU), masked/scattered store
    #pragma unroll
    for (int n = 0; n < 2; ++n) {
        const int col = n0 + wc * 32 + n * 16 + l15;
        const float bv = biasp[col];
        #pragma unroll
        for (int m = 0; m < 2; ++m) {
            #pragma unroll
            for (int r = 0; r < 4; ++r) {
                const int row_local = wr * 32 + m * 16 + l16 * 4 + r;
                if constexpr (EXPERT) {
                    if (mloc0 + row_local >= count) continue;
                }
                float v = acc[m][n][r] + bv;
                if constexpr (GELU_OUT) v = gelu_exact(v);
                int orow = m0 + row_local;
                if constexpr (SCATTER_OUT) orow = perm[orow];
                if constexpr (OUT_BF16)
                    ((bf16_t*)Cout)[(size_t)orow * N + col] = (bf16_t)v;
                else
                    ((float*)Cout)[(size_t)orow * N + col] = v;
            }
        }
    }
}

extern "C" void kernel_launch(void* const* d_in, const int* in_sizes, int n_in,
                              void* d_out, int out_size, void* d_ws, size_t ws_size,
                              hipStream_t stream) {
    const float* x     = (const float*)d_in[0];
    const int*   genre = (const int*)  d_in[1];
    const float* W1    = (const float*)d_in[2];
    const float* b1    = (const float*)d_in[3];
    const float* W2    = (const float*)d_in[4];
    const float* b2    = (const float*)d_in[5];
    const float* Wa    = (const float*)d_in[6];
    const float* ba    = (const float*)d_in[7];
    const float* Wb    = (const float*)d_in[8];
    const float* bb    = (const float*)d_in[9];
    float* out = (float*)d_out;

    char* ws = (char*)d_ws;
    const size_t MB = 1 << 20;
    bf16_t* W1t = (bf16_t*)(ws);                 // 1 MB  [1024][512]
    bf16_t* W2t = (bf16_t*)(ws + 1 * MB);        // 2 MB  [1024][1024]
    bf16_t* Wat = (bf16_t*)(ws + 3 * MB);        // 32 MB [16][1024][1024]
    bf16_t* Wbt = (bf16_t*)(ws + 35 * MB);       // 32 MB
    bf16_t* xb  = (bf16_t*)(ws + 67 * MB);       // 4 MB  [4096][512]
    bf16_t* s1b = (bf16_t*)(ws + 71 * MB);       // 8 MB  [4096][1024] (reused as h)
    bf16_t* sb  = (bf16_t*)(ws + 79 * MB);       // 8 MB
    int*    perm    = (int*)(ws + 87 * MB);      // 16 KB
    int*    offsets = (int*)(ws + 87 * MB + 65536);
    bf16_t* hb = s1b;  // s1 dead after GEMM2

    build_perm_kernel<<<1, 256, 0, stream>>>(genre, perm, offsets);
    convert_x_kernel<<<BATCH * INDIM / (256 * 8), 256, 0, stream>>>(x, xb);
    transpose_w_kernel<<<dim3(INDIM / 32, NDIM / 64, 1),  256, 0, stream>>>(W1, W1t, INDIM, NDIM);
    transpose_w_kernel<<<dim3(NDIM / 32, NDIM / 64, 1),   256, 0, stream>>>(W2, W2t, NDIM, NDIM);
    transpose_w_kernel<<<dim3(NDIM / 32, NDIM / 64, NG),  256, 0, stream>>>(Wa, Wat, NDIM, NDIM);
    transpose_w_kernel<<<dim3(NDIM / 32, NDIM / 64, NG),  256, 0, stream>>>(Wb, Wbt, NDIM, NDIM);

    // trunk: s1 = gelu(x @ W1 + b1)
    gemm128_kernel<false, false, true, false, true><<<dim3(32, 8), 1024, 0, stream>>>(
        xb, W1t, b1, s1b, INDIM, nullptr, nullptr);
    // trunk: s = gelu(s1 @ W2 + b2)
    gemm128_kernel<false, false, true, false, true><<<dim3(32, 8), 1024, 0, stream>>>(
        s1b, W2t, b2, sb, NDIM, nullptr, nullptr);
    // experts: h[perm-space] = gelu(s[perm] @ Wa[g] + ba[g])
    gemm128_kernel<true, true, true, false, true><<<dim3(48, 8), 1024, 0, stream>>>(
        sb, Wat, ba, hb, NDIM, perm, offsets);
    // experts: out[perm] = h @ Wb[g] + bb[g]
    gemm128_kernel<true, false, false, true, false><<<dim3(48, 8), 1024, 0, stream>>>(
        hb, Wbt, bb, out, NDIM, perm, offsets);
}